// Round 1
// baseline (1219.258 us; speedup 1.0000x reference)
//
#include <hip/hip_runtime.h>
#include <stdint.h>

#define N_HEADS 8
#define IN_DIM 1024
#define ATTN_DIM 128
#define OUT_DIM 1024
#define BATCH 32768

typedef float  floatx4 __attribute__((ext_vector_type(4)));
typedef short  short8  __attribute__((ext_vector_type(8)));

__device__ __forceinline__ unsigned short f2b(float f) {
  union { float f; uint32_t u; } c; c.f = f;
  uint32_t u = c.u;
  uint32_t r = (u + 0x7FFFu + ((u >> 16) & 1u)) >> 16;  // RNE
  return (unsigned short)r;
}
__device__ __forceinline__ float b2f(unsigned short b) {
  union { uint32_t u; float f; } c; c.u = ((uint32_t)b) << 16;
  return c.f;
}

__device__ __forceinline__ void load_lds16(const void* g, void* l) {
  // async global->LDS, 16B/lane; LDS dest is wave-uniform base + lane*16
  __builtin_amdgcn_global_load_lds((__attribute__((address_space(1))) void*)g,
                                   (__attribute__((address_space(3))) void*)l,
                                   16, 0, 0);
}

// Stage a [128 rows x 64 k] bf16 tile into LDS.
// BF=true: source already bf16 (ws), use global_load_lds dwordx4.
// BF=false: source fp32, VGPR round-trip + convert.
template<bool BF>
__device__ __forceinline__ void stage_tile(const unsigned short* gb, const float* gf,
                                           int ld, size_t row0, int kt,
                                           unsigned short* lds, int tid) {
  if constexpr (BF) {
    const unsigned short* g = gb + row0 * (size_t)ld + kt;
    int w = tid >> 6, lane = tid & 63;
#pragma unroll
    for (int r = 0; r < 4; r++) {
      int rowblk = w * 8 + r * 32;                       // 8 rows per wave-instr
      const unsigned short* gp = g + (size_t)(rowblk + (lane >> 3)) * ld + (lane & 7) * 8;
      load_lds16(gp, lds + (size_t)rowblk * 64);         // wave-uniform LDS base
    }
  } else {
    const float* g = gf + row0 * (size_t)ld + kt;
#pragma unroll
    for (int it = 0; it < 8; it++) {
      int idx = it * 1024 + tid * 4;
      int row = idx >> 6, col = idx & 63;
      float4 v = *(const float4*)(g + (size_t)row * ld + col);
      *(ushort4*)(lds + row * 64 + col) =
          make_ushort4(f2b(v.x), f2b(v.y), f2b(v.z), f2b(v.w));
    }
  }
}

// 128x128x64 MFMA step: 4 waves in 2x2, each wave 64x64 via 4x4 of 16x16x32.
__device__ __forceinline__ void mma_tile(const unsigned short* Xs, const unsigned short* Ws,
                                         floatx4 acc[4][4], int wr, int wc, int lq, int lr) {
#pragma unroll
  for (int s = 0; s < 2; s++) {
    short8 a[4], b[4];
#pragma unroll
    for (int i = 0; i < 4; i++)
      a[i] = *(const short8*)(Xs + (64 * wr + 16 * i + lr) * 64 + 32 * s + 8 * lq);
#pragma unroll
    for (int j = 0; j < 4; j++)
      b[j] = *(const short8*)(Ws + (64 * wc + 16 * j + lr) * 64 + 32 * s + 8 * lq);
#pragma unroll
    for (int i = 0; i < 4; i++)
#pragma unroll
      for (int j = 0; j < 4; j++)
        acc[i][j] = __builtin_amdgcn_mfma_f32_16x16x32_bf16(a[i], b[j], acc[i][j], 0, 0, 0);
  }
}

// Phase 1: per 128-row tile: Q = x@Wq^T (+bq) kept in LDS (bf16);
// per head K = x@Wk_h^T, fold dot(Q,K+bk) per row; softmax over 8 heads -> attn.
template<bool BF>
__launch_bounds__(256, 2)
__global__ void attn_phase1(const unsigned short* xb, const float* xf,
                            const unsigned short* wqb, const float* wqf,
                            const unsigned short* wkb, const float* wkf,
                            const float* bq, const float* bk, float* attn) {
  __shared__ unsigned short Xs[128 * 64];
  __shared__ unsigned short Ws[128 * 64];
  __shared__ unsigned short Qs[128 * 128];
  __shared__ float dots[128 * 8];
  int tid = threadIdx.x;
  size_t row0 = (size_t)blockIdx.x * 128;
  int w = tid >> 6, lane = tid & 63;
  int wr = w >> 1, wc = w & 1, lq = lane >> 4, lr = lane & 15;

  for (int i = tid; i < 1024; i += 256) dots[i] = 0.0f;

  floatx4 acc[4][4];
#pragma unroll
  for (int i = 0; i < 4; i++)
#pragma unroll
    for (int j = 0; j < 4; j++) acc[i][j] = (floatx4){0.f, 0.f, 0.f, 0.f};

  // ---- Q pass ----
  for (int kt = 0; kt < IN_DIM; kt += 64) {
    stage_tile<BF>(xb, xf, IN_DIM, row0, kt, Xs, tid);
    stage_tile<BF>(wqb, wqf, IN_DIM, 0, kt, Ws, tid);
    __syncthreads();
    mma_tile(Xs, Ws, acc, wr, wc, lq, lr);
    __syncthreads();
  }
  // C/D layout: col=lane&15, row=(lane>>4)*4+reg
#pragma unroll
  for (int i = 0; i < 4; i++)
#pragma unroll
    for (int j = 0; j < 4; j++)
#pragma unroll
      for (int r = 0; r < 4; r++) {
        int row_l = 64 * wr + 16 * i + 4 * lq + r;
        int col_l = 64 * wc + 16 * j + lr;
        Qs[row_l * 128 + col_l] = f2b(acc[i][j][r] + bq[col_l]);
      }
  __syncthreads();

  // ---- per-head K pass + gating dot ----
  for (int h = 0; h < N_HEADS; h++) {
#pragma unroll
    for (int i = 0; i < 4; i++)
#pragma unroll
      for (int j = 0; j < 4; j++) acc[i][j] = (floatx4){0.f, 0.f, 0.f, 0.f};
    for (int kt = 0; kt < IN_DIM; kt += 64) {
      stage_tile<BF>(xb, xf, IN_DIM, row0, kt, Xs, tid);
      if constexpr (BF)
        stage_tile<BF>(wkb + (size_t)h * ATTN_DIM * IN_DIM, nullptr, IN_DIM, 0, kt, Ws, tid);
      else
        stage_tile<BF>(nullptr, wkf + (size_t)h * ATTN_DIM * IN_DIM, IN_DIM, 0, kt, Ws, tid);
      __syncthreads();
      mma_tile(Xs, Ws, acc, wr, wc, lq, lr);
      __syncthreads();
    }
#pragma unroll
    for (int i = 0; i < 4; i++)
#pragma unroll
      for (int r = 0; r < 4; r++) {
        int row_l = 64 * wr + 16 * i + 4 * lq + r;
        float p = 0.0f;
#pragma unroll
        for (int j = 0; j < 4; j++) {
          int col_l = 64 * wc + 16 * j + lr;
          p += (acc[i][j][r] + bk[h * ATTN_DIM + col_l]) * b2f(Qs[row_l * 128 + col_l]);
        }
        p += __shfl_xor(p, 1);
        p += __shfl_xor(p, 2);
        p += __shfl_xor(p, 4);
        p += __shfl_xor(p, 8);
        if (lr == 0) atomicAdd(&dots[row_l * 8 + h], p);
      }
  }
  __syncthreads();

  if (tid < 128) {
    float d[8];
    float m = -1e30f;
#pragma unroll
    for (int h = 0; h < 8; h++) {
      d[h] = dots[tid * 8 + h] * 0.088388347648318447f;  // 1/sqrt(128)
      m = fmaxf(m, d[h]);
    }
    float s = 0.f;
#pragma unroll
    for (int h = 0; h < 8; h++) { d[h] = __expf(d[h] - m); s += d[h]; }
    float inv = 1.0f / s;
    size_t rg = row0 + tid;
#pragma unroll
    for (int h = 0; h < 8; h++) attn[rg * 8 + h] = d[h] * inv;
  }
}

// Phase 2: per (128-row x 128-col) tile, loop heads: V_h tile via MFMA K-loop,
// fold attn[r,h]*(V+bv) into output accumulator. values never materialized.
template<bool BF>
__launch_bounds__(256, 2)
__global__ void attn_phase2(const unsigned short* xb, const float* xf,
                            const unsigned short* wvb, const float* wvf,
                            const float* bv, const float* attn, float* out) {
  __shared__ unsigned short Xs[128 * 64];
  __shared__ unsigned short Ws[128 * 64];
  __shared__ float As[128 * 8];
  int tid = threadIdx.x;
  int bt = blockIdx.x >> 3;
  int ot = blockIdx.x & 7;   // consecutive blocks share the X tile (L2 reuse)
  size_t row0 = (size_t)bt * 128;
  int col0 = ot * 128;
  int w = tid >> 6, lane = tid & 63;
  int wr = w >> 1, wc = w & 1, lq = lane >> 4, lr = lane & 15;

  for (int i = tid; i < 1024; i += 256) As[i] = attn[row0 * 8 + i];

  floatx4 oacc[4][4];
#pragma unroll
  for (int i = 0; i < 4; i++)
#pragma unroll
    for (int j = 0; j < 4; j++) oacc[i][j] = (floatx4){0.f, 0.f, 0.f, 0.f};

  for (int h = 0; h < N_HEADS; h++) {
    floatx4 acc[4][4];
#pragma unroll
    for (int i = 0; i < 4; i++)
#pragma unroll
      for (int j = 0; j < 4; j++) acc[i][j] = (floatx4){0.f, 0.f, 0.f, 0.f};
    for (int kt = 0; kt < IN_DIM; kt += 64) {
      stage_tile<BF>(xb, xf, IN_DIM, row0, kt, Xs, tid);
      if constexpr (BF)
        stage_tile<BF>(wvb + ((size_t)h * OUT_DIM + col0) * IN_DIM, nullptr, IN_DIM, 0, kt, Ws, tid);
      else
        stage_tile<BF>(nullptr, wvf + ((size_t)h * OUT_DIM + col0) * IN_DIM, IN_DIM, 0, kt, Ws, tid);
      __syncthreads();
      mma_tile(Xs, Ws, acc, wr, wc, lq, lr);
      __syncthreads();
    }
#pragma unroll
    for (int i = 0; i < 4; i++)
#pragma unroll
      for (int r = 0; r < 4; r++) {
        int row_l = 64 * wr + 16 * i + 4 * lq + r;
        float a = As[row_l * 8 + h];
#pragma unroll
        for (int j = 0; j < 4; j++) {
          int col_l = 64 * wc + 16 * j + lr;
          oacc[i][j][r] += a * (acc[i][j][r] + bv[h * OUT_DIM + col0 + col_l]);
        }
      }
  }
#pragma unroll
  for (int i = 0; i < 4; i++)
#pragma unroll
    for (int r = 0; r < 4; r++) {
      int row_l = 64 * wr + 16 * i + 4 * lq + r;
#pragma unroll
      for (int j = 0; j < 4; j++) {
        int col_l = 64 * wc + 16 * j + lr;
        out[(row0 + row_l) * (size_t)OUT_DIM + col0 + col_l] = oacc[i][j][r];
      }
    }
}

__global__ void cvt_bf16(const float4* __restrict__ in, ushort4* __restrict__ out, int n4) {
  int i = blockIdx.x * blockDim.x + threadIdx.x;
  int stride = gridDim.x * blockDim.x;
  for (; i < n4; i += stride) {
    float4 v = in[i];
    out[i] = make_ushort4(f2b(v.x), f2b(v.y), f2b(v.z), f2b(v.w));
  }
}

extern "C" void kernel_launch(void* const* d_in, const int* in_sizes, int n_in,
                              void* d_out, int out_size, void* d_ws, size_t ws_size,
                              hipStream_t stream) {
  const float* x  = (const float*)d_in[0];
  const float* Wq = (const float*)d_in[1];
  const float* bq = (const float*)d_in[2];
  const float* Wk = (const float*)d_in[3];
  const float* bk = (const float*)d_in[4];
  const float* Wv = (const float*)d_in[5];
  const float* bv = (const float*)d_in[6];
  float* out = (float*)d_out;

  char* ws = (char*)d_ws;
  float* attn = (float*)ws;
  size_t off = (size_t)BATCH * N_HEADS * 4;                       // 1 MB gate buffer
  unsigned short* xb  = (unsigned short*)(ws + off); off += (size_t)BATCH * IN_DIM * 2;
  unsigned short* wqb = (unsigned short*)(ws + off); off += (size_t)ATTN_DIM * IN_DIM * 2;
  unsigned short* wkb = (unsigned short*)(ws + off); off += (size_t)N_HEADS * ATTN_DIM * IN_DIM * 2;
  unsigned short* wvb = (unsigned short*)(ws + off); off += (size_t)N_HEADS * OUT_DIM * IN_DIM * 2;
  bool fast = ws_size >= off;  // ~84 MB needed for bf16 prepass path

  if (fast) {
    cvt_bf16<<<8192, 256, 0, stream>>>((const float4*)x,  (ushort4*)xb,  BATCH * IN_DIM / 4);
    cvt_bf16<<<128,  256, 0, stream>>>((const float4*)Wq, (ushort4*)wqb, ATTN_DIM * IN_DIM / 4);
    cvt_bf16<<<1024, 256, 0, stream>>>((const float4*)Wk, (ushort4*)wkb, N_HEADS * ATTN_DIM * IN_DIM / 4);
    cvt_bf16<<<8192, 256, 0, stream>>>((const float4*)Wv, (ushort4*)wvb, N_HEADS * OUT_DIM * IN_DIM / 4);
    attn_phase1<true><<<BATCH / 128, 256, 0, stream>>>(xb, nullptr, wqb, nullptr, wkb, nullptr, bq, bk, attn);
    attn_phase2<true><<<(BATCH / 128) * (OUT_DIM / 128), 256, 0, stream>>>(xb, nullptr, wvb, nullptr, bv, attn, out);
  } else {
    attn_phase1<false><<<BATCH / 128, 256, 0, stream>>>(nullptr, x, nullptr, Wq, nullptr, Wk, bq, bk, attn);
    attn_phase2<false><<<(BATCH / 128) * (OUT_DIM / 128), 256, 0, stream>>>(nullptr, x, nullptr, Wv, bv, attn, out);
  }
}

// Round 3
// 953.251 us; speedup vs baseline: 1.2791x; 1.2791x over previous
//
#include <hip/hip_runtime.h>
#include <stdint.h>

#define N_HEADS 8
#define IN_DIM 1024
#define ATTN_DIM 128
#define OUT_DIM 1024
#define BATCH 32768

typedef float  floatx4 __attribute__((ext_vector_type(4)));
typedef short  short8  __attribute__((ext_vector_type(8)));

__device__ __forceinline__ unsigned short f2b(float f) {
  union { float f; uint32_t u; } c; c.f = f;
  uint32_t u = c.u;
  uint32_t r = (u + 0x7FFFu + ((u >> 16) & 1u)) >> 16;  // RNE
  return (unsigned short)r;
}
__device__ __forceinline__ float b2f(unsigned short b) {
  union { uint32_t u; float f; } c; c.u = ((uint32_t)b) << 16;
  return c.f;
}

__device__ __forceinline__ void load_lds16(const void* g, void* l) {
  __builtin_amdgcn_global_load_lds((__attribute__((address_space(1))) void*)g,
                                   (__attribute__((address_space(3))) void*)l,
                                   16, 0, 0);
}

// Stage a [128 rows x 64 k] bf16 tile into LDS with XOR chunk swizzle:
// LDS chunk position p of row r holds global k-chunk (p ^ (r&7)).
// Makes MFMA fragment reads hit all 32 banks evenly (conflict-free).
template<bool BF>
__device__ __forceinline__ void stage_tile(const unsigned short* gb, const float* gf,
                                           int ld, size_t row0, int kt,
                                           unsigned short* lds, int tid) {
  if constexpr (BF) {
    const unsigned short* g = gb + row0 * (size_t)ld + kt;
    int w = tid >> 6, lane = tid & 63;
    int lrow = lane >> 3;                  // 0..7 within the 8-row slab
    int lchunk = (lane & 7) ^ lrow;        // swizzled source chunk
#pragma unroll
    for (int r = 0; r < 4; r++) {
      int rowblk = w * 8 + r * 32;         // multiple of 8 -> (row&7)==lrow
      const unsigned short* gp = g + (size_t)(rowblk + lrow) * ld + lchunk * 8;
      load_lds16(gp, lds + (size_t)rowblk * 64);  // wave-uniform LDS base
    }
  } else {
    const float* g = gf + row0 * (size_t)ld + kt;
#pragma unroll
    for (int it = 0; it < 8; it++) {
      int idx = it * 1024 + tid * 4;
      int row = idx >> 6, col = idx & 63;
      int sc = (((col >> 3) ^ (row & 7)) << 3) + (col & 7);
      float4 v = *(const float4*)(g + (size_t)row * ld + col);
      *(ushort4*)(lds + row * 64 + sc) =
          make_ushort4(f2b(v.x), f2b(v.y), f2b(v.z), f2b(v.w));
    }
  }
}

// 128x128x64 MFMA step: 4 waves in 2x2, each wave 64x64 via 4x4 of 16x16x32.
// Reads use the XOR-swizzled chunk index (conflict-free).
__device__ __forceinline__ void mma_tile(const unsigned short* Xs, const unsigned short* Ws,
                                         floatx4 acc[4][4], int wr, int wc, int lq, int lr) {
#pragma unroll
  for (int s = 0; s < 2; s++) {
    short8 a[4], b[4];
    int ch = ((4 * s + lq) ^ (lr & 7)) * 8;
#pragma unroll
    for (int i = 0; i < 4; i++)
      a[i] = *(const short8*)(Xs + (64 * wr + 16 * i + lr) * 64 + ch);
#pragma unroll
    for (int j = 0; j < 4; j++)
      b[j] = *(const short8*)(Ws + (64 * wc + 16 * j + lr) * 64 + ch);
#pragma unroll
    for (int i = 0; i < 4; i++)
#pragma unroll
      for (int j = 0; j < 4; j++)
        acc[i][j] = __builtin_amdgcn_mfma_f32_16x16x32_bf16(a[i], b[j], acc[i][j], 0, 0, 0);
  }
}

// ---- Phase 1a: Q = x@Wq^T + bq, stored bf16 into Qb (ws scratch) ----
__launch_bounds__(256, 2)
__global__ void q_gemm(const unsigned short* __restrict__ xb,
                       const unsigned short* __restrict__ wqb,
                       const float* __restrict__ bq, unsigned short* __restrict__ Qb) {
  __shared__ unsigned short Xs[128 * 64];
  __shared__ unsigned short Ws[128 * 64];
  int tid = threadIdx.x;
  size_t row0 = (size_t)blockIdx.x * 128;
  int w = tid >> 6, lane = tid & 63;
  int wr = w >> 1, wc = w & 1, lq = lane >> 4, lr = lane & 15;

  floatx4 acc[4][4];
#pragma unroll
  for (int i = 0; i < 4; i++)
#pragma unroll
    for (int j = 0; j < 4; j++) acc[i][j] = (floatx4){0.f, 0.f, 0.f, 0.f};

  for (int kt = 0; kt < IN_DIM; kt += 64) {
    stage_tile<true>(xb, nullptr, IN_DIM, row0, kt, Xs, tid);
    stage_tile<true>(wqb, nullptr, IN_DIM, 0, kt, Ws, tid);
    __syncthreads();
    mma_tile(Xs, Ws, acc, wr, wc, lq, lr);
    __syncthreads();
  }
  // C/D layout: col=lane&15, row=(lane>>4)*4+reg
#pragma unroll
  for (int i = 0; i < 4; i++)
#pragma unroll
    for (int j = 0; j < 4; j++)
#pragma unroll
      for (int r = 0; r < 4; r++) {
        int row_l = 64 * wr + 16 * i + 4 * lq + r;
        int col_l = 64 * wc + 16 * j + lr;
        Qb[(row0 + row_l) * 128 + col_l] = f2b(acc[i][j][r] + bq[col_l]);
      }
}

// ---- Phase 1b: per (tile, head): K = x@Wk_h^T, dots[r,h] = sum_c (K+bk)*Q ----
__launch_bounds__(256, 2)
__global__ void k_dot(const unsigned short* __restrict__ xb,
                      const unsigned short* __restrict__ wkb,
                      const unsigned short* __restrict__ Qb,
                      const float* __restrict__ bk, float* __restrict__ dots) {
  __shared__ unsigned short Xs[128 * 64];
  __shared__ unsigned short Ws[128 * 64];
  __shared__ float dsum[128];
  int b = blockIdx.x;
  int bt = (b >> 6) * 8 + (b & 7);  // 8 head-blocks of one tile share an XCD
  int h  = (b >> 3) & 7;
  size_t row0 = (size_t)bt * 128;
  int tid = threadIdx.x;
  int w = tid >> 6, lane = tid & 63;
  int wr = w >> 1, wc = w & 1, lq = lane >> 4, lr = lane & 15;

  if (tid < 128) dsum[tid] = 0.0f;

  floatx4 acc[4][4];
#pragma unroll
  for (int i = 0; i < 4; i++)
#pragma unroll
    for (int j = 0; j < 4; j++) acc[i][j] = (floatx4){0.f, 0.f, 0.f, 0.f};

  const unsigned short* wkh = wkb + (size_t)h * ATTN_DIM * IN_DIM;
  for (int kt = 0; kt < IN_DIM; kt += 64) {
    stage_tile<true>(xb, nullptr, IN_DIM, row0, kt, Xs, tid);
    stage_tile<true>(wkh, nullptr, IN_DIM, 0, kt, Ws, tid);
    __syncthreads();
    mma_tile(Xs, Ws, acc, wr, wc, lq, lr);
    __syncthreads();
  }
#pragma unroll
  for (int i = 0; i < 4; i++)
#pragma unroll
    for (int r = 0; r < 4; r++) {
      int row_l = 64 * wr + 16 * i + 4 * lq + r;
      float p = 0.0f;
#pragma unroll
      for (int j = 0; j < 4; j++) {
        int col_l = 64 * wc + 16 * j + lr;
        p += (acc[i][j][r] + bk[h * ATTN_DIM + col_l]) *
             b2f(Qb[(row0 + row_l) * 128 + col_l]);
      }
      p += __shfl_xor(p, 1);
      p += __shfl_xor(p, 2);
      p += __shfl_xor(p, 4);
      p += __shfl_xor(p, 8);
      if (lr == 0) atomicAdd(&dsum[row_l], p);
    }
  __syncthreads();
  if (tid < 128) dots[(row0 + tid) * 8 + h] = dsum[tid];
}

// ---- Phase 1c: softmax over 8 heads, in place ----
__global__ void softmax8(float* __restrict__ dots) {
  int r = blockIdx.x * blockDim.x + threadIdx.x;
  float d[8];
  float m = -1e30f;
#pragma unroll
  for (int h = 0; h < 8; h++) {
    d[h] = dots[r * 8 + h] * 0.088388347648318447f;  // 1/sqrt(128)
    m = fmaxf(m, d[h]);
  }
  float s = 0.f;
#pragma unroll
  for (int h = 0; h < 8; h++) { d[h] = __expf(d[h] - m); s += d[h]; }
  float inv = 1.0f / s;
#pragma unroll
  for (int h = 0; h < 8; h++) dots[r * 8 + h] = d[h] * inv;
}

// ---- Phase 2: per (128-row x 128-col) tile, loop heads: fold attn*(X@Wv_h^T+bv) ----
template<bool BF>
__launch_bounds__(256, 2)
__global__ void attn_phase2(const unsigned short* xb, const float* xf,
                            const unsigned short* wvb, const float* wvf,
                            const float* __restrict__ bv, const float* __restrict__ attn,
                            float* __restrict__ out) {
  __shared__ unsigned short Xs[128 * 64];
  __shared__ unsigned short Ws[128 * 64];
  __shared__ float As[128 * 8];
  __shared__ float bvs[8 * 128];
  int b = blockIdx.x;
  int bt = (b >> 6) * 8 + (b & 7);  // 8 col-blocks of one row-tile share an XCD
  int ot = (b >> 3) & 7;
  size_t row0 = (size_t)bt * 128;
  int col0 = ot * 128;
  int tid = threadIdx.x;
  int w = tid >> 6, lane = tid & 63;
  int wr = w >> 1, wc = w & 1, lq = lane >> 4, lr = lane & 15;

  for (int i = tid; i < 1024; i += 256) {
    As[i]  = attn[row0 * 8 + i];
    bvs[i] = bv[(i >> 7) * OUT_DIM + col0 + (i & 127)];
  }
  __syncthreads();

  floatx4 oacc[4][4];
#pragma unroll
  for (int i = 0; i < 4; i++)
#pragma unroll
    for (int j = 0; j < 4; j++) oacc[i][j] = (floatx4){0.f, 0.f, 0.f, 0.f};

  for (int h = 0; h < N_HEADS; h++) {
    floatx4 acc[4][4];
#pragma unroll
    for (int i = 0; i < 4; i++)
#pragma unroll
      for (int j = 0; j < 4; j++) acc[i][j] = (floatx4){0.f, 0.f, 0.f, 0.f};
    for (int kt = 0; kt < IN_DIM; kt += 64) {
      stage_tile<BF>(xb, xf, IN_DIM, row0, kt, Xs, tid);
      if constexpr (BF)
        stage_tile<BF>(wvb + ((size_t)h * OUT_DIM + col0) * IN_DIM, nullptr, IN_DIM, 0, kt, Ws, tid);
      else
        stage_tile<BF>(nullptr, wvf + ((size_t)h * OUT_DIM + col0) * IN_DIM, IN_DIM, 0, kt, Ws, tid);
      __syncthreads();
      mma_tile(Xs, Ws, acc, wr, wc, lq, lr);
      __syncthreads();
    }
#pragma unroll
    for (int i = 0; i < 4; i++)
#pragma unroll
      for (int r = 0; r < 4; r++) {
        int row_l = 64 * wr + 16 * i + 4 * lq + r;
        float a = As[row_l * 8 + h];
#pragma unroll
        for (int j = 0; j < 4; j++) {
          int col_l = 64 * wc + 16 * j + lr;
          oacc[i][j][r] += a * (acc[i][j][r] + bvs[h * 128 + col_l]);
        }
      }
  }
#pragma unroll
  for (int i = 0; i < 4; i++)
#pragma unroll
    for (int r = 0; r < 4; r++) {
      int row_l = 64 * wr + 16 * i + 4 * lq + r;
#pragma unroll
      for (int j = 0; j < 4; j++) {
        int col_l = 64 * wc + 16 * j + lr;
        out[(row0 + row_l) * (size_t)OUT_DIM + col0 + col_l] = oacc[i][j][r];
      }
    }
}

// ---- fused phase 1 (fallback when ws can't hold Qb): Q in LDS, loop heads ----
template<bool BF>
__launch_bounds__(256, 2)
__global__ void attn_phase1_fused(const unsigned short* xb, const float* xf,
                                  const unsigned short* wqb, const float* wqf,
                                  const unsigned short* wkb, const float* wkf,
                                  const float* bq, const float* bk, float* attn) {
  __shared__ unsigned short Xs[128 * 64];
  __shared__ unsigned short Ws[128 * 64];
  __shared__ unsigned short Qs[128 * 128];
  __shared__ float dots[128 * 8];
  int tid = threadIdx.x;
  size_t row0 = (size_t)blockIdx.x * 128;
  int w = tid >> 6, lane = tid & 63;
  int wr = w >> 1, wc = w & 1, lq = lane >> 4, lr = lane & 15;

  for (int i = tid; i < 1024; i += 256) dots[i] = 0.0f;

  floatx4 acc[4][4];
#pragma unroll
  for (int i = 0; i < 4; i++)
#pragma unroll
    for (int j = 0; j < 4; j++) acc[i][j] = (floatx4){0.f, 0.f, 0.f, 0.f};

  for (int kt = 0; kt < IN_DIM; kt += 64) {
    stage_tile<BF>(xb, xf, IN_DIM, row0, kt, Xs, tid);
    stage_tile<BF>(wqb, wqf, IN_DIM, 0, kt, Ws, tid);
    __syncthreads();
    mma_tile(Xs, Ws, acc, wr, wc, lq, lr);
    __syncthreads();
  }
#pragma unroll
  for (int i = 0; i < 4; i++)
#pragma unroll
    for (int j = 0; j < 4; j++)
#pragma unroll
      for (int r = 0; r < 4; r++) {
        int row_l = 64 * wr + 16 * i + 4 * lq + r;
        int col_l = 64 * wc + 16 * j + lr;
        Qs[row_l * 128 + col_l] = f2b(acc[i][j][r] + bq[col_l]);
      }
  __syncthreads();

  for (int h = 0; h < N_HEADS; h++) {
#pragma unroll
    for (int i = 0; i < 4; i++)
#pragma unroll
      for (int j = 0; j < 4; j++) acc[i][j] = (floatx4){0.f, 0.f, 0.f, 0.f};
    for (int kt = 0; kt < IN_DIM; kt += 64) {
      stage_tile<BF>(xb, xf, IN_DIM, row0, kt, Xs, tid);
      if constexpr (BF)
        stage_tile<BF>(wkb + (size_t)h * ATTN_DIM * IN_DIM, nullptr, IN_DIM, 0, kt, Ws, tid);
      else
        stage_tile<BF>(nullptr, wkf + (size_t)h * ATTN_DIM * IN_DIM, IN_DIM, 0, kt, Ws, tid);
      __syncthreads();
      mma_tile(Xs, Ws, acc, wr, wc, lq, lr);
      __syncthreads();
    }
#pragma unroll
    for (int i = 0; i < 4; i++)
#pragma unroll
      for (int r = 0; r < 4; r++) {
        int row_l = 64 * wr + 16 * i + 4 * lq + r;
        float p = 0.0f;
#pragma unroll
        for (int j = 0; j < 4; j++) {
          int col_l = 64 * wc + 16 * j + lr;
          p += (acc[i][j][r] + bk[h * ATTN_DIM + col_l]) * b2f(Qs[row_l * 128 + col_l]);
        }
        p += __shfl_xor(p, 1);
        p += __shfl_xor(p, 2);
        p += __shfl_xor(p, 4);
        p += __shfl_xor(p, 8);
        if (lr == 0) atomicAdd(&dots[row_l * 8 + h], p);
      }
    __syncthreads();
  }

  if (tid < 128) {
    float d[8];
    float m = -1e30f;
#pragma unroll
    for (int h = 0; h < 8; h++) {
      d[h] = dots[tid * 8 + h] * 0.088388347648318447f;
      m = fmaxf(m, d[h]);
    }
    float s = 0.f;
#pragma unroll
    for (int h = 0; h < 8; h++) { d[h] = __expf(d[h] - m); s += d[h]; }
    float inv = 1.0f / s;
    size_t rg = row0 + tid;
#pragma unroll
    for (int h = 0; h < 8; h++) attn[rg * 8 + h] = d[h] * inv;
  }
}

__global__ void cvt_bf16(const float4* __restrict__ in, ushort4* __restrict__ out, int n4) {
  int i = blockIdx.x * blockDim.x + threadIdx.x;
  int stride = gridDim.x * blockDim.x;
  for (; i < n4; i += stride) {
    float4 v = in[i];
    out[i] = make_ushort4(f2b(v.x), f2b(v.y), f2b(v.z), f2b(v.w));
  }
}

extern "C" void kernel_launch(void* const* d_in, const int* in_sizes, int n_in,
                              void* d_out, int out_size, void* d_ws, size_t ws_size,
                              hipStream_t stream) {
  const float* x  = (const float*)d_in[0];
  const float* Wq = (const float*)d_in[1];
  const float* bq = (const float*)d_in[2];
  const float* Wk = (const float*)d_in[3];
  const float* bk = (const float*)d_in[4];
  const float* Wv = (const float*)d_in[5];
  const float* bv = (const float*)d_in[6];
  float* out = (float*)d_out;

  // ws layout — d_out is NEVER used as scratch (its re-poison is not
  // reliably ordered against graph replays; see R2 post-mortem).
  char* ws = (char*)d_ws;
  float* attn = (float*)ws;                                        // dots -> attn in place
  size_t off = (size_t)BATCH * N_HEADS * 4;                        // 1 MB
  unsigned short* xb  = (unsigned short*)(ws + off); off += (size_t)BATCH * IN_DIM * 2;       // 64 MB
  unsigned short* wqb = (unsigned short*)(ws + off); off += (size_t)ATTN_DIM * IN_DIM * 2;    // 0.25 MB
  unsigned short* wkb = (unsigned short*)(ws + off); off += (size_t)N_HEADS * ATTN_DIM * IN_DIM * 2; // 2 MB
  unsigned short* wvb = (unsigned short*)(ws + off); off += (size_t)N_HEADS * OUT_DIM * IN_DIM * 2;  // 16 MB
  size_t off_noq = off;
  unsigned short* Qb  = (unsigned short*)(ws + off); off += (size_t)BATCH * ATTN_DIM * 2;     // 8 MB

  if (ws_size >= off_noq) {
    cvt_bf16<<<8192, 256, 0, stream>>>((const float4*)x,  (ushort4*)xb,  BATCH * IN_DIM / 4);
    cvt_bf16<<<128,  256, 0, stream>>>((const float4*)Wq, (ushort4*)wqb, ATTN_DIM * IN_DIM / 4);
    cvt_bf16<<<1024, 256, 0, stream>>>((const float4*)Wk, (ushort4*)wkb, N_HEADS * ATTN_DIM * IN_DIM / 4);
    cvt_bf16<<<8192, 256, 0, stream>>>((const float4*)Wv, (ushort4*)wvb, N_HEADS * OUT_DIM * IN_DIM / 4);
    if (ws_size >= off) {
      // split phase 1: q_gemm (256 blocks) -> k_dot (2048 blocks) -> softmax
      q_gemm<<<BATCH / 128, 256, 0, stream>>>(xb, wqb, bq, Qb);
      k_dot<<<(BATCH / 128) * N_HEADS, 256, 0, stream>>>(xb, wkb, Qb, bk, attn);
      softmax8<<<BATCH / 256, 256, 0, stream>>>(attn);
    } else {
      attn_phase1_fused<true><<<BATCH / 128, 256, 0, stream>>>(
          xb, nullptr, wqb, nullptr, wkb, nullptr, bq, bk, attn);
    }
    attn_phase2<true><<<(BATCH / 128) * (OUT_DIM / 128), 256, 0, stream>>>(
        xb, nullptr, wvb, nullptr, bv, attn, out);
  } else {
    attn_phase1_fused<false><<<BATCH / 128, 256, 0, stream>>>(
        nullptr, x, nullptr, Wq, nullptr, Wk, bq, bk, attn);
    attn_phase2<false><<<(BATCH / 128) * (OUT_DIM / 128), 256, 0, stream>>>(
        nullptr, x, nullptr, Wv, bv, attn, out);
  }
}